// Round 11
// baseline (313.678 us; speedup 1.0000x reference)
//
#include <hip/hip_runtime.h>
#include <hip/hip_bf16.h>
#include <math.h>

#define M_TOTAL 16384   // B*S = 4*4096
#define D_MODEL 1024
#define N_QKV   3072
#define CURV    0.15f
#define EPS_F   1e-6f

typedef __attribute__((ext_vector_type(8))) short short8v;
typedef __attribute__((ext_vector_type(4))) float f32x4;

__device__ __forceinline__ void gl_lds16(const void* g, void* l) {
    __builtin_amdgcn_global_load_lds(
        (const __attribute__((address_space(1))) void*)g,
        (__attribute__((address_space(3))) void*)l, 16, 0, 0);
}
__device__ __forceinline__ unsigned short f2bf_bits(float x) {
    __hip_bfloat16 t = __float2bfloat16(x);
    return *(unsigned short*)&t;
}
__device__ __forceinline__ float bf2f(unsigned short u) {
    return __uint_as_float(((unsigned)u) << 16);
}

// ---------------------------------------------------------------------------
// cast fp32 -> bf16, 4 elems/thread
// ---------------------------------------------------------------------------
__global__ __launch_bounds__(256)
void cast_f32_bf16(const float* __restrict__ in, unsigned short* __restrict__ out,
                   int ngroups)
{
    int i = blockIdx.x * 256 + threadIdx.x;
    if (i >= ngroups) return;
    float4 u = ((const float4*)in)[i];
    ushort4 r;
    r.x = f2bf_bits(u.x); r.y = f2bf_bits(u.y);
    r.z = f2bf_bits(u.z); r.w = f2bf_bits(u.w);
    ((ushort4*)out)[i] = r;
}

// ---------------------------------------------------------------------------
// transpose + cast: W[K][N] fp32  ->  Wt[N][K] bf16.
// ---------------------------------------------------------------------------
__global__ __launch_bounds__(256)
void transpose_cast(const float* __restrict__ W, unsigned short* __restrict__ Wt,
                    int K, int N)
{
    __shared__ float tile[32][33];
    const int n0 = blockIdx.x * 32;
    const int k0 = blockIdx.y * 32;
    const int tx = threadIdx.x & 31;
    const int ty = threadIdx.x >> 5;
    #pragma unroll
    for (int i = 0; i < 32; i += 8)
        tile[ty + i][tx] = W[(size_t)(k0 + ty + i) * N + n0 + tx];
    __syncthreads();
    #pragma unroll
    for (int i = 0; i < 32; i += 8)
        Wt[(size_t)(n0 + ty + i) * K + k0 + tx] = f2bf_bits(tile[tx][ty + i]);
}

// ---------------------------------------------------------------------------
// 256x256 bf16 MFMA GEMM — R11: R5's register-pipelined 4-phase schedule
// (best measured) with three codegen fixes:
//  (a) QUAD ks-OUTER: dep distance 8 between MFMAs hitting the same acc
//      (was 1: back-to-back dependent pairs stall the matrix pipe at latency).
//      Per-acc FP order still ks0->ks1 -> bitwise-identical output.
//  (b) 2-tile static unroll: buf is compile-time.
//  (c) 8 precomputed LDS base indices (A/B x ks x buf), every ds_read =
//      base + compile-time immediate (m*2048B <= 14336) -> zero addr VALU.
// Schedule per tile (u static, T = T2+u):
//   p0: issue b23 -> lgkm(4)+schedbar -> QUAD(0,0)
//   p1: issue a4-7 -> lgkm(8)+schedbar -> QUAD(0,2) -> bar -> STAGE B(T+2)
//   p2: lgkm(0)+schedbar -> QUAD(4,0) -> bar -> STAGE A(T+2)
//   p3: vmcnt(8|0) -> bar -> issue T+1 frags (other buf) -> schedbar -> QUAD(4,2)
// ---------------------------------------------------------------------------
template<int OUT_BF16>
__global__ __launch_bounds__(512, 2)
void gemm256_r11(const unsigned short* __restrict__ A,
                 const unsigned short* __restrict__ Bt,
                 const float* __restrict__ bias,
                 void* __restrict__ Cout,
                 int M, int N, int K, int nbx)
{
    __shared__ __align__(16) short smem_s[65536];   // 128 KiB

    const int t    = threadIdx.x;
    const int w    = t >> 6;
    const int lane = t & 63;
    const int wm   = w >> 2;          // 0..1
    const int wn   = w & 3;           // 0..3
    const int lr   = lane & 15;
    const int hi   = lane >> 4;       // 0..3
    const int lo7  = lane & 7;

    // bijective XCD chunk swizzle (gridDim.x % 8 == 0)
    const int nwg  = gridDim.x;
    const int orig = blockIdx.x;
    const int wgid = (orig & 7) * (nwg >> 3) + (orig >> 3);
    const int by = wgid / nbx, bx = wgid % nbx;
    const int bm0 = by * 256, bn0 = bx * 256;

    const int nt = K >> 6;            // 16 for K=1024 (even)

    // staging: LDS dest linear, source col pre-swizzled (rule #21)
    const int srow = t >> 3;                        // 0..63
    const int scol = ((t & 7) ^ (srow & 7)) * 8;    // swizzled element col
    const unsigned short* Ag = A  + (size_t)(bm0 + srow) * K + scol;
    const unsigned short* Bg = Bt + (size_t)(bn0 + srow) * K + scol;
    const int wbase = w * 1024;

    auto STAGE = [&](int which, int half, int tile) {
        const unsigned short* g0 = (which ? Bg : Ag)
                                 + (size_t)(half * 128) * K + (size_t)tile * 64;
        char* d0 = (char*)smem_s + ((tile & 1) * 65536 + which * 32768
                                    + half * 16384 + wbase);
        gl_lds16(g0,                d0);
        gl_lds16(g0 + (size_t)64*K, d0 + 8192);
    };

    // ---- precomputed LDS read bases (indices into smem_s, shorts) ----
    const int c0 = (hi ^ lo7) * 8;           // ks=0 swizzled chunk
    const int c1 = ((4 + hi) ^ lo7) * 8;     // ks=1 swizzled chunk
    const int rA = wm * 8192 + lr * 64;
    const int rB = 16384 + (wn >> 1) * 8192 + (wn & 1) * 4096 + lr * 64;
    const int ibA00 = rA + c0,          ibA10 = rA + c1;            // buf0
    const int ibA01 = rA + c0 + 32768,  ibA11 = rA + c1 + 32768;    // buf1
    const int ibB00 = rB + c0,          ibB10 = rB + c1;
    const int ibB01 = rB + c0 + 32768,  ibB11 = rB + c1 + 32768;

    short8v a[8][2], b[4][2];
    f32x4 acc[8][4] = {};

    auto QUAD = [&](int mlo, int nlo) {      // ks-OUTER: dep distance 8
        __builtin_amdgcn_s_setprio(1);
        #pragma unroll
        for (int ks = 0; ks < 2; ++ks)
            #pragma unroll
            for (int mi = 0; mi < 4; ++mi)
                #pragma unroll
                for (int ni = 0; ni < 2; ++ni)
                    acc[mlo+mi][nlo+ni] = __builtin_amdgcn_mfma_f32_16x16x32_bf16(
                        a[mlo+mi][ks], b[nlo+ni][ks], acc[mlo+mi][nlo+ni], 0, 0, 0);
        __builtin_amdgcn_s_setprio(0);
    };

    // ---- prologue: stage tiles 0,1; tile 0 resident; preload 12 frags ----
    STAGE(0,0,0); STAGE(0,1,0); STAGE(1,0,0); STAGE(1,1,0);
    STAGE(0,0,1); STAGE(0,1,1); STAGE(1,0,1); STAGE(1,1,1);
    asm volatile("s_waitcnt vmcnt(8)" ::: "memory");
    __builtin_amdgcn_s_barrier();
    #pragma unroll
    for (int m = 0; m < 4; ++m) {
        a[m][0] = *(const short8v*)&smem_s[ibA00 + m*1024];
        a[m][1] = *(const short8v*)&smem_s[ibA10 + m*1024];
    }
    b[0][0] = *(const short8v*)&smem_s[ibB00];
    b[0][1] = *(const short8v*)&smem_s[ibB10];
    b[1][0] = *(const short8v*)&smem_s[ibB00 + 1024];
    b[1][1] = *(const short8v*)&smem_s[ibB10 + 1024];

    for (int T2 = 0; T2 < nt; T2 += 2) {
        #pragma unroll
        for (int u = 0; u < 2; ++u) {
            const int T   = T2 + u;
            const int iA0 = u ? ibA01 : ibA00;   // this buf, ks0
            const int iA1 = u ? ibA11 : ibA10;   // this buf, ks1
            const int iB0 = u ? ibB01 : ibB00;
            const int iB1 = u ? ibB11 : ibB10;
            const int jA0 = u ? ibA00 : ibA01;   // other buf (tile T+1)
            const int jA1 = u ? ibA10 : ibA11;
            const int jB0 = u ? ibB00 : ibB01;
            const int jB1 = u ? ibB10 : ibB11;

            // ---- p0: issue b23; drain prev 12 frags (keep 4); Q(0,0) ----
            b[2][0] = *(const short8v*)&smem_s[iB0 + 2048];
            b[2][1] = *(const short8v*)&smem_s[iB1 + 2048];
            b[3][0] = *(const short8v*)&smem_s[iB0 + 3072];
            b[3][1] = *(const short8v*)&smem_s[iB1 + 3072];
            asm volatile("s_waitcnt lgkmcnt(4)" ::: "memory");
            __builtin_amdgcn_sched_barrier(0);
            QUAD(0,0);
            // ---- p1: issue a4-7; drain b23 (keep 8); Q(0,2); stage B(T+2) --
            #pragma unroll
            for (int m = 4; m < 8; ++m) {
                a[m][0] = *(const short8v*)&smem_s[iA0 + m*1024];
                a[m][1] = *(const short8v*)&smem_s[iA1 + m*1024];
            }
            asm volatile("s_waitcnt lgkmcnt(8)" ::: "memory");
            __builtin_amdgcn_sched_barrier(0);
            QUAD(0,2);
            __builtin_amdgcn_s_barrier();        // all buf.B reads retired
            if (T+2 < nt) { STAGE(1,0,T+2); STAGE(1,1,T+2); }
            // ---- p2: drain a4-7; Q(4,0); stage A(T+2) ----
            asm volatile("s_waitcnt lgkmcnt(0)" ::: "memory");
            __builtin_amdgcn_sched_barrier(0);
            QUAD(4,0);
            __builtin_amdgcn_s_barrier();        // all buf.A reads retired
            if (T+2 < nt) { STAGE(0,0,T+2); STAGE(0,1,T+2); }
            // ---- p3: T+1 residency gate; issue T+1 frags; Q(4,2) ----
            if (T+2 < nt) { asm volatile("s_waitcnt vmcnt(8)" ::: "memory"); }
            else          { asm volatile("s_waitcnt vmcnt(0)" ::: "memory"); }
            __builtin_amdgcn_s_barrier();        // other buf (T+1) readable
            if (T+1 < nt) {
                #pragma unroll
                for (int m = 0; m < 4; ++m) {
                    a[m][0] = *(const short8v*)&smem_s[jA0 + m*1024];
                    a[m][1] = *(const short8v*)&smem_s[jA1 + m*1024];
                }
                b[0][0] = *(const short8v*)&smem_s[jB0];
                b[0][1] = *(const short8v*)&smem_s[jB1];
                b[1][0] = *(const short8v*)&smem_s[jB0 + 1024];
                b[1][1] = *(const short8v*)&smem_s[jB1 + 1024];
            }
            __builtin_amdgcn_sched_barrier(0);   // pin: issue before Q(4,2)
            QUAD(4,2);
        }
    }

    // ---- epilogue: C/D layout col=lane&15, row=hi*4+j ----
    const int r0 = bm0 + wm*128 + hi*4;
    const int cb = bn0 + wn*64 + lr;
    float bv[4];
    #pragma unroll
    for (int n = 0; n < 4; ++n) bv[n] = bias[cb + n*16];
    if (OUT_BF16) {
        unsigned short* Cb = (unsigned short*)Cout;
        #pragma unroll
        for (int m = 0; m < 8; ++m)
            #pragma unroll
            for (int j = 0; j < 4; ++j) {
                unsigned short* rp = Cb + (size_t)(r0 + m*16 + j) * N;
                #pragma unroll
                for (int n = 0; n < 4; ++n)
                    rp[cb + n*16] = f2bf_bits(acc[m][n][j] + bv[n]);
            }
    } else {
        float* Cf = (float*)Cout;
        #pragma unroll
        for (int m = 0; m < 8; ++m)
            #pragma unroll
            for (int j = 0; j < 4; ++j) {
                float* rp = Cf + (size_t)(r0 + m*16 + j) * N;
                #pragma unroll
                for (int n = 0; n < 4; ++n)
                    rp[cb + n*16] = acc[m][n][j] + bv[n];
            }
    }
}

// ---------------------------------------------------------------------------
// R9 attention (unchanged): one wave per position, all-register, no LDS.
// ---------------------------------------------------------------------------
__global__ __launch_bounds__(256)
void attn_mfma_kernel(const unsigned short* __restrict__ qkv,
                      unsigned short* __restrict__ aout)
{
    const int l  = threadIdx.x & 63;
    const int wv = threadIdx.x >> 6;
    const int p  = blockIdx.x * 4 + wv;
    const int lr = l & 15;
    const int hi = l >> 4;
    const unsigned short* base = qkv + (size_t)p * N_QKV;

    short8v qf0 = *(const short8v*)(base +        lr*64 +      hi*8);
    short8v qf1 = *(const short8v*)(base +        lr*64 + 32 + hi*8);
    short8v kf0 = *(const short8v*)(base + 1024 + lr*64 +      hi*8);
    short8v kf1 = *(const short8v*)(base + 1024 + lr*64 + 32 + hi*8);

    f32x4 s = {};
    s = __builtin_amdgcn_mfma_f32_16x16x32_bf16(kf0, qf0, s, 0, 0, 0);
    s = __builtin_amdgcn_mfma_f32_16x16x32_bf16(kf1, qf1, s, 0, 0, 0);

    float qsq = 0.f, ksq = 0.f;
    #pragma unroll
    for (int i = 0; i < 8; ++i) {
        float q0 = bf2f((unsigned short)qf0[i]), q1 = bf2f((unsigned short)qf1[i]);
        float k0 = bf2f((unsigned short)kf0[i]), k1 = bf2f((unsigned short)kf1[i]);
        qsq = fmaf(q0, q0, fmaf(q1, q1, qsq));
        ksq = fmaf(k0, k0, fmaf(k1, k1, ksq));
    }
    qsq += __shfl_xor(qsq, 16); qsq += __shfl_xor(qsq, 32);
    ksq += __shfl_xor(ksq, 16); ksq += __shfl_xor(ksq, 32);

    const float mq = sqrtf(qsq);

    float P[4];
    #pragma unroll
    for (int j = 0; j < 4; ++j) {
        float ksg = __shfl(ksq, hi * 4 + j);
        float dsq = fmaxf(qsq + ksg - 2.f * s[j], 0.f);
        dsq = dsq * (1.f + CURV * cosf(sqrtf(dsq + EPS_F)));
        P[j] = mq * sqrtf(ksg) / (dsq + EPS_F);
    }
    float mx = fmaxf(fmaxf(P[0], P[1]), fmaxf(P[2], P[3]));
    mx = fmaxf(mx, __shfl_xor(mx, 16));
    mx = fmaxf(mx, __shfl_xor(mx, 32));
    float sm = 0.f;
    #pragma unroll
    for (int j = 0; j < 4; ++j) { P[j] = expf(P[j] - mx); sm += P[j]; }
    sm += __shfl_xor(sm, 16); sm += __shfl_xor(sm, 32);
    const float inv = 1.f / sm;

    unsigned int w0 = (unsigned)f2bf_bits(P[0] * inv)
                    | ((unsigned)f2bf_bits(P[1] * inv) << 16);
    unsigned int w1 = (unsigned)f2bf_bits(P[2] * inv)
                    | ((unsigned)f2bf_bits(P[3] * inv) << 16);
    const int s0 = lr + (((2 * hi)     & 3) << 4);
    const int s1 = lr + (((2 * hi + 1) & 3) << 4);
    unsigned int a0 = __shfl((int)w0, s0), a1 = __shfl((int)w1, s0);
    unsigned int a2 = __shfl((int)w0, s1), a3 = __shfl((int)w1, s1);
    if (hi >= 2) { a0 = a1 = a2 = a3 = 0; }
    unsigned int pa_u[4] = {a0, a1, a2, a3};
    short8v pa = *(short8v*)pa_u;

    const unsigned short* vb = base + 2048;
    unsigned short* orow = aout + (size_t)p * D_MODEL;
    #pragma unroll
    for (int c = 0; c < 4; ++c) {
        unsigned int bu[4];
        #pragma unroll
        for (int e2 = 0; e2 < 4; ++e2) {
            int g0 = (hi * 8 + e2 * 2) & 15;
            int g1 = (hi * 8 + e2 * 2 + 1) & 15;
            unsigned int lo = vb[g0 * 64 + c * 16 + lr];
            unsigned int hi16 = vb[g1 * 64 + c * 16 + lr];
            bu[e2] = lo | (hi16 << 16);
        }
        short8v bv = *(short8v*)bu;
        f32x4 o = {};
        o = __builtin_amdgcn_mfma_f32_16x16x32_bf16(pa, bv, o, 0, 0, 0);
        #pragma unroll
        for (int j = 0; j < 4; ++j)
            orow[(hi * 4 + j) * 64 + c * 16 + lr] = f2bf_bits(o[j]);
    }
}

// ---------------------------------------------------------------------------
extern "C" void kernel_launch(void* const* d_in, const int* in_sizes, int n_in,
                              void* d_out, int out_size, void* d_ws, size_t ws_size,
                              hipStream_t stream)
{
    const float* x     = (const float*)d_in[0];   // 16384 x 1024
    const float* W_qkv = (const float*)d_in[1];   // 1024 x 3072
    const float* b_qkv = (const float*)d_in[2];   // 3072
    const float* W_out = (const float*)d_in[3];   // 1024 x 1024
    const float* b_out = (const float*)d_in[4];   // 1024
    float* out = (float*)d_out;                   // 16384 x 1024

    // workspace: [0,96M) qkv bf16 | [96M,128M) xb/ab bf16 | Wt1 6M | Wt2 2M
    char* ws = (char*)d_ws;
    unsigned short* qkvb = (unsigned short*)ws;
    unsigned short* xb   = (unsigned short*)(ws + (size_t)M_TOTAL * N_QKV * 2);
    unsigned short* ab   = xb;   // alias: xb dead after GEMM1
    unsigned short* Wt1  = (unsigned short*)(ws + (size_t)M_TOTAL * N_QKV * 2
                                                + (size_t)M_TOTAL * D_MODEL * 2);
    unsigned short* Wt2  = Wt1 + (size_t)N_QKV * D_MODEL;

    // 0a) cast x -> bf16
    {
        int ngroups = M_TOTAL * D_MODEL / 4;
        cast_f32_bf16<<<ngroups / 256, 256, 0, stream>>>(x, xb, ngroups);
    }
    // 0b) transpose+cast weights
    {
        dim3 g(N_QKV / 32, D_MODEL / 32);
        transpose_cast<<<g, 256, 0, stream>>>(W_qkv, Wt1, D_MODEL, N_QKV);
        dim3 g2(D_MODEL / 32, D_MODEL / 32);
        transpose_cast<<<g2, 256, 0, stream>>>(W_out, Wt2, D_MODEL, D_MODEL);
    }

    // 1) qkv = x @ W_qkv + b_qkv  (bf16 out)
    {
        int nbx = N_QKV / 256;                 // 12
        int nwg = (M_TOTAL / 256) * nbx;       // 768 (%8==0)
        gemm256_r11<1><<<nwg, 512, 0, stream>>>(xb, Wt1, b_qkv, qkvb,
                                                M_TOTAL, N_QKV, D_MODEL, nbx);
    }

    // 2) per-position head attention — 1 wave/position, 4 positions/block
    attn_mfma_kernel<<<M_TOTAL / 4, 256, 0, stream>>>(qkvb, ab);

    // 3) out = ab @ W_out + b_out  (fp32 out)
    {
        int nbx = D_MODEL / 256;               // 4
        int nwg = (M_TOTAL / 256) * nbx;       // 256 (%8==0)
        gemm256_r11<0><<<nwg, 512, 0, stream>>>(ab, Wt2, b_out, out,
                                                M_TOTAL, D_MODEL, D_MODEL, nbx);
    }
}

// Round 12
// 193.170 us; speedup vs baseline: 1.6238x; 1.6238x over previous
//
#include <hip/hip_runtime.h>
#include <hip/hip_bf16.h>
#include <math.h>

#define M_TOTAL 16384   // B*S = 4*4096
#define D_MODEL 1024
#define N_QKV   3072
#define CURV    0.15f
#define EPS_F   1e-6f

typedef __attribute__((ext_vector_type(8))) short short8v;
typedef __attribute__((ext_vector_type(4))) float f32x4;

__device__ __forceinline__ void gl_lds16(const void* g, void* l) {
    __builtin_amdgcn_global_load_lds(
        (const __attribute__((address_space(1))) void*)g,
        (__attribute__((address_space(3))) void*)l, 16, 0, 0);
}
__device__ __forceinline__ unsigned short f2bf_bits(float x) {
    __hip_bfloat16 t = __float2bfloat16(x);
    return *(unsigned short*)&t;
}
__device__ __forceinline__ float bf2f(unsigned short u) {
    return __uint_as_float(((unsigned)u) << 16);
}

// ---------------------------------------------------------------------------
// cast fp32 -> bf16, 4 elems/thread
// ---------------------------------------------------------------------------
__global__ __launch_bounds__(256)
void cast_f32_bf16(const float* __restrict__ in, unsigned short* __restrict__ out,
                   int ngroups)
{
    int i = blockIdx.x * 256 + threadIdx.x;
    if (i >= ngroups) return;
    float4 u = ((const float4*)in)[i];
    ushort4 r;
    r.x = f2bf_bits(u.x); r.y = f2bf_bits(u.y);
    r.z = f2bf_bits(u.z); r.w = f2bf_bits(u.w);
    ((ushort4*)out)[i] = r;
}

// ---------------------------------------------------------------------------
// transpose + cast: W[K][N] fp32  ->  Wt[N][K] bf16.
// ---------------------------------------------------------------------------
__global__ __launch_bounds__(256)
void transpose_cast(const float* __restrict__ W, unsigned short* __restrict__ Wt,
                    int K, int N)
{
    __shared__ float tile[32][33];
    const int n0 = blockIdx.x * 32;
    const int k0 = blockIdx.y * 32;
    const int tx = threadIdx.x & 31;
    const int ty = threadIdx.x >> 5;
    #pragma unroll
    for (int i = 0; i < 32; i += 8)
        tile[ty + i][tx] = W[(size_t)(k0 + ty + i) * N + n0 + tx];
    __syncthreads();
    #pragma unroll
    for (int i = 0; i < 32; i += 8)
        Wt[(size_t)(n0 + ty + i) * K + k0 + tx] = f2bf_bits(tile[tx][ty + i]);
}

// ---------------------------------------------------------------------------
// 256x256 bf16 MFMA GEMM — R5's register-pipelined 4-phase schedule (best
// measured: 119.5us GEMM1), with EXACTLY ONE change (R12): QUAD is ks-OUTER,
// so MFMAs hitting the same acc are 8 apart (was back-to-back, dep dist 1).
// Per-acc FP order still ks0->ks1 -> bitwise-identical output.
// ---------------------------------------------------------------------------
template<int OUT_BF16>
__global__ __launch_bounds__(512, 2)
void gemm256_8ph(const unsigned short* __restrict__ A,
                 const unsigned short* __restrict__ Bt,
                 const float* __restrict__ bias,
                 void* __restrict__ Cout,
                 int M, int N, int K, int nbx)
{
    __shared__ __align__(16) short smem_s[65536];   // 128 KiB

    const int t    = threadIdx.x;
    const int w    = t >> 6;
    const int lane = t & 63;
    const int wm   = w >> 2;
    const int wn   = w & 3;
    const int lr   = lane & 15;
    const int hi   = lane >> 4;
    const int lo7  = lane & 7;

    const int nwg  = gridDim.x;
    const int orig = blockIdx.x;
    const int wgid = (orig & 7) * (nwg >> 3) + (orig >> 3);
    const int by = wgid / nbx, bx = wgid % nbx;
    const int bm0 = by * 256, bn0 = bx * 256;

    const int nt = K >> 6;

    const int srow = t >> 3;
    const int scol = ((t & 7) ^ (srow & 7)) * 8;
    const unsigned short* Ag = A  + (size_t)(bm0 + srow) * K + scol;
    const unsigned short* Bg = Bt + (size_t)(bn0 + srow) * K + scol;
    const int wbase = w * 1024;

    auto STAGE = [&](int which, int half, int tile) {
        const unsigned short* g0 = (which ? Bg : Ag)
                                 + (size_t)(half * 128) * K + (size_t)tile * 64;
        char* d0 = (char*)smem_s + ((tile & 1) * 65536 + which * 32768
                                    + half * 16384 + wbase);
        gl_lds16(g0,                d0);
        gl_lds16(g0 + (size_t)64*K, d0 + 8192);
    };

    short8v a[8][2], b[4][2];
    f32x4 acc[8][4] = {};

    auto LDA = [&](int buf, int m, int ks) {
        a[m][ks] = *(const short8v*)&smem_s[buf*32768 + wm*8192
                        + (m*16 + lr)*64 + (((ks*4 + hi) ^ lo7) * 8)];
    };
    auto LDB = [&](int buf, int n, int ks) {
        b[n][ks] = *(const short8v*)&smem_s[buf*32768 + 16384 + (wn>>1)*8192
                        + ((wn&1)*64 + n*16 + lr)*64 + (((ks*4 + hi) ^ lo7) * 8)];
    };
    auto QUAD = [&](int mlo, int nlo) {      // R12: ks-OUTER (dep distance 8)
        __builtin_amdgcn_s_setprio(1);
        #pragma unroll
        for (int ks = 0; ks < 2; ++ks)
            #pragma unroll
            for (int mi = 0; mi < 4; ++mi)
                #pragma unroll
                for (int ni = 0; ni < 2; ++ni)
                    acc[mlo+mi][nlo+ni] = __builtin_amdgcn_mfma_f32_16x16x32_bf16(
                        a[mlo+mi][ks], b[nlo+ni][ks], acc[mlo+mi][nlo+ni], 0, 0, 0);
        __builtin_amdgcn_s_setprio(0);
    };

    STAGE(0,0,0); STAGE(0,1,0); STAGE(1,0,0); STAGE(1,1,0);
    STAGE(0,0,1); STAGE(0,1,1); STAGE(1,0,1); STAGE(1,1,1);
    asm volatile("s_waitcnt vmcnt(8)" ::: "memory");
    __builtin_amdgcn_s_barrier();
    #pragma unroll
    for (int m = 0; m < 4; ++m) { LDA(0,m,0); LDA(0,m,1); }
    LDB(0,0,0); LDB(0,0,1); LDB(0,1,0); LDB(0,1,1);

    for (int T = 0; T < nt; ++T) {
        const int buf  = T & 1;
        const int nbuf = buf ^ 1;
        LDB(buf,2,0); LDB(buf,2,1); LDB(buf,3,0); LDB(buf,3,1);
        asm volatile("s_waitcnt lgkmcnt(4)" ::: "memory");
        __builtin_amdgcn_sched_barrier(0);
        QUAD(0,0);
        #pragma unroll
        for (int m = 4; m < 8; ++m) { LDA(buf,m,0); LDA(buf,m,1); }
        asm volatile("s_waitcnt lgkmcnt(8)" ::: "memory");
        __builtin_amdgcn_sched_barrier(0);
        QUAD(0,2);
        __builtin_amdgcn_s_barrier();
        if (T+2 < nt) { STAGE(1,0,T+2); STAGE(1,1,T+2); }
        asm volatile("s_waitcnt lgkmcnt(0)" ::: "memory");
        __builtin_amdgcn_sched_barrier(0);
        QUAD(4,0);
        __builtin_amdgcn_s_barrier();
        if (T+2 < nt) { STAGE(0,0,T+2); STAGE(0,1,T+2); }
        if (T+2 < nt) { asm volatile("s_waitcnt vmcnt(8)" ::: "memory"); }
        else          { asm volatile("s_waitcnt vmcnt(0)" ::: "memory"); }
        __builtin_amdgcn_s_barrier();
        if (T+1 < nt) {
            #pragma unroll
            for (int m = 0; m < 4; ++m) { LDA(nbuf,m,0); LDA(nbuf,m,1); }
            LDB(nbuf,0,0); LDB(nbuf,0,1); LDB(nbuf,1,0); LDB(nbuf,1,1);
        }
        __builtin_amdgcn_sched_barrier(0);
        QUAD(4,2);
    }

    const int r0 = bm0 + wm*128 + hi*4;
    const int cb = bn0 + wn*64 + lr;
    float bv[4];
    #pragma unroll
    for (int n = 0; n < 4; ++n) bv[n] = bias[cb + n*16];
    if (OUT_BF16) {
        unsigned short* Cb = (unsigned short*)Cout;
        #pragma unroll
        for (int m = 0; m < 8; ++m)
            #pragma unroll
            for (int j = 0; j < 4; ++j) {
                unsigned short* rp = Cb + (size_t)(r0 + m*16 + j) * N;
                #pragma unroll
                for (int n = 0; n < 4; ++n)
                    rp[cb + n*16] = f2bf_bits(acc[m][n][j] + bv[n]);
            }
    } else {
        float* Cf = (float*)Cout;
        #pragma unroll
        for (int m = 0; m < 8; ++m)
            #pragma unroll
            for (int j = 0; j < 4; ++j) {
                float* rp = Cf + (size_t)(r0 + m*16 + j) * N;
                #pragma unroll
                for (int n = 0; n < 4; ++n)
                    rp[cb + n*16] = acc[m][n][j] + bv[n];
            }
    }
}

// ---------------------------------------------------------------------------
// R9 attention (unchanged): one wave per position, all-register, no LDS.
// ---------------------------------------------------------------------------
__global__ __launch_bounds__(256)
void attn_mfma_kernel(const unsigned short* __restrict__ qkv,
                      unsigned short* __restrict__ aout)
{
    const int l  = threadIdx.x & 63;
    const int wv = threadIdx.x >> 6;
    const int p  = blockIdx.x * 4 + wv;
    const int lr = l & 15;
    const int hi = l >> 4;
    const unsigned short* base = qkv + (size_t)p * N_QKV;

    short8v qf0 = *(const short8v*)(base +        lr*64 +      hi*8);
    short8v qf1 = *(const short8v*)(base +        lr*64 + 32 + hi*8);
    short8v kf0 = *(const short8v*)(base + 1024 + lr*64 +      hi*8);
    short8v kf1 = *(const short8v*)(base + 1024 + lr*64 + 32 + hi*8);

    f32x4 s = {};
    s = __builtin_amdgcn_mfma_f32_16x16x32_bf16(kf0, qf0, s, 0, 0, 0);
    s = __builtin_amdgcn_mfma_f32_16x16x32_bf16(kf1, qf1, s, 0, 0, 0);

    float qsq = 0.f, ksq = 0.f;
    #pragma unroll
    for (int i = 0; i < 8; ++i) {
        float q0 = bf2f((unsigned short)qf0[i]), q1 = bf2f((unsigned short)qf1[i]);
        float k0 = bf2f((unsigned short)kf0[i]), k1 = bf2f((unsigned short)kf1[i]);
        qsq = fmaf(q0, q0, fmaf(q1, q1, qsq));
        ksq = fmaf(k0, k0, fmaf(k1, k1, ksq));
    }
    qsq += __shfl_xor(qsq, 16); qsq += __shfl_xor(qsq, 32);
    ksq += __shfl_xor(ksq, 16); ksq += __shfl_xor(ksq, 32);

    const float mq = sqrtf(qsq);

    float P[4];
    #pragma unroll
    for (int j = 0; j < 4; ++j) {
        float ksg = __shfl(ksq, hi * 4 + j);
        float dsq = fmaxf(qsq + ksg - 2.f * s[j], 0.f);
        dsq = dsq * (1.f + CURV * cosf(sqrtf(dsq + EPS_F)));
        P[j] = mq * sqrtf(ksg) / (dsq + EPS_F);
    }
    float mx = fmaxf(fmaxf(P[0], P[1]), fmaxf(P[2], P[3]));
    mx = fmaxf(mx, __shfl_xor(mx, 16));
    mx = fmaxf(mx, __shfl_xor(mx, 32));
    float sm = 0.f;
    #pragma unroll
    for (int j = 0; j < 4; ++j) { P[j] = expf(P[j] - mx); sm += P[j]; }
    sm += __shfl_xor(sm, 16); sm += __shfl_xor(sm, 32);
    const float inv = 1.f / sm;

    unsigned int w0 = (unsigned)f2bf_bits(P[0] * inv)
                    | ((unsigned)f2bf_bits(P[1] * inv) << 16);
    unsigned int w1 = (unsigned)f2bf_bits(P[2] * inv)
                    | ((unsigned)f2bf_bits(P[3] * inv) << 16);
    const int s0 = lr + (((2 * hi)     & 3) << 4);
    const int s1 = lr + (((2 * hi + 1) & 3) << 4);
    unsigned int a0 = __shfl((int)w0, s0), a1 = __shfl((int)w1, s0);
    unsigned int a2 = __shfl((int)w0, s1), a3 = __shfl((int)w1, s1);
    if (hi >= 2) { a0 = a1 = a2 = a3 = 0; }
    unsigned int pa_u[4] = {a0, a1, a2, a3};
    short8v pa = *(short8v*)pa_u;

    const unsigned short* vb = base + 2048;
    unsigned short* orow = aout + (size_t)p * D_MODEL;
    #pragma unroll
    for (int c = 0; c < 4; ++c) {
        unsigned int bu[4];
        #pragma unroll
        for (int e2 = 0; e2 < 4; ++e2) {
            int g0 = (hi * 8 + e2 * 2) & 15;
            int g1 = (hi * 8 + e2 * 2 + 1) & 15;
            unsigned int lo = vb[g0 * 64 + c * 16 + lr];
            unsigned int hi16 = vb[g1 * 64 + c * 16 + lr];
            bu[e2] = lo | (hi16 << 16);
        }
        short8v bv = *(short8v*)bu;
        f32x4 o = {};
        o = __builtin_amdgcn_mfma_f32_16x16x32_bf16(pa, bv, o, 0, 0, 0);
        #pragma unroll
        for (int j = 0; j < 4; ++j)
            orow[(hi * 4 + j) * 64 + c * 16 + lr] = f2bf_bits(o[j]);
    }
}

// ---------------------------------------------------------------------------
extern "C" void kernel_launch(void* const* d_in, const int* in_sizes, int n_in,
                              void* d_out, int out_size, void* d_ws, size_t ws_size,
                              hipStream_t stream)
{
    const float* x     = (const float*)d_in[0];   // 16384 x 1024
    const float* W_qkv = (const float*)d_in[1];   // 1024 x 3072
    const float* b_qkv = (const float*)d_in[2];   // 3072
    const float* W_out = (const float*)d_in[3];   // 1024 x 1024
    const float* b_out = (const float*)d_in[4];   // 1024
    float* out = (float*)d_out;                   // 16384 x 1024

    // workspace: [0,96M) qkv bf16 | [96M,128M) xb/ab bf16 | Wt1 6M | Wt2 2M
    char* ws = (char*)d_ws;
    unsigned short* qkvb = (unsigned short*)ws;
    unsigned short* xb   = (unsigned short*)(ws + (size_t)M_TOTAL * N_QKV * 2);
    unsigned short* ab   = xb;   // alias: xb dead after GEMM1
    unsigned short* Wt1  = (unsigned short*)(ws + (size_t)M_TOTAL * N_QKV * 2
                                                + (size_t)M_TOTAL * D_MODEL * 2);
    unsigned short* Wt2  = Wt1 + (size_t)N_QKV * D_MODEL;

    // 0a) cast x -> bf16
    {
        int ngroups = M_TOTAL * D_MODEL / 4;
        cast_f32_bf16<<<ngroups / 256, 256, 0, stream>>>(x, xb, ngroups);
    }
    // 0b) transpose+cast weights
    {
        dim3 g(N_QKV / 32, D_MODEL / 32);
        transpose_cast<<<g, 256, 0, stream>>>(W_qkv, Wt1, D_MODEL, N_QKV);
        dim3 g2(D_MODEL / 32, D_MODEL / 32);
        transpose_cast<<<g2, 256, 0, stream>>>(W_out, Wt2, D_MODEL, D_MODEL);
    }

    // 1) qkv = x @ W_qkv + b_qkv  (bf16 out)
    {
        int nbx = N_QKV / 256;                 // 12
        int nwg = (M_TOTAL / 256) * nbx;       // 768 (%8==0)
        gemm256_8ph<1><<<nwg, 512, 0, stream>>>(xb, Wt1, b_qkv, qkvb,
                                                M_TOTAL, N_QKV, D_MODEL, nbx);
    }

    // 2) per-position head attention — 1 wave/position, 4 positions/block
    attn_mfma_kernel<<<M_TOTAL / 4, 256, 0, stream>>>(qkvb, ab);

    // 3) out = ab @ W_out + b_out  (fp32 out)
    {
        int nbx = D_MODEL / 256;               // 4
        int nwg = (M_TOTAL / 256) * nbx;       // 256 (%8==0)
        gemm256_8ph<0><<<nwg, 512, 0, stream>>>(ab, Wt2, b_out, out,
                                                M_TOTAL, D_MODEL, D_MODEL, nbx);
    }
}

// Round 13
// 191.045 us; speedup vs baseline: 1.6419x; 1.0111x over previous
//
#include <hip/hip_runtime.h>
#include <hip/hip_bf16.h>
#include <math.h>

#define M_TOTAL 16384   // B*S = 4*4096
#define D_MODEL 1024
#define N_QKV   3072
#define CURV    0.15f
#define EPS_F   1e-6f

typedef __attribute__((ext_vector_type(8))) short short8v;
typedef __attribute__((ext_vector_type(4))) float f32x4;

__device__ __forceinline__ void gl_lds16(const void* g, void* l) {
    __builtin_amdgcn_global_load_lds(
        (const __attribute__((address_space(1))) void*)g,
        (__attribute__((address_space(3))) void*)l, 16, 0, 0);
}
__device__ __forceinline__ unsigned short f2bf_bits(float x) {
    __hip_bfloat16 t = __float2bfloat16(x);
    return *(unsigned short*)&t;
}
__device__ __forceinline__ float bf2f(unsigned short u) {
    return __uint_as_float(((unsigned)u) << 16);
}

// ---------------------------------------------------------------------------
// cast fp32 -> bf16, 4 elems/thread
// ---------------------------------------------------------------------------
__global__ __launch_bounds__(256)
void cast_f32_bf16(const float* __restrict__ in, unsigned short* __restrict__ out,
                   int ngroups)
{
    int i = blockIdx.x * 256 + threadIdx.x;
    if (i >= ngroups) return;
    float4 u = ((const float4*)in)[i];
    ushort4 r;
    r.x = f2bf_bits(u.x); r.y = f2bf_bits(u.y);
    r.z = f2bf_bits(u.z); r.w = f2bf_bits(u.w);
    ((ushort4*)out)[i] = r;
}

// ---------------------------------------------------------------------------
// transpose + cast: W[K][N] fp32  ->  Wt[N][K] bf16.
// ---------------------------------------------------------------------------
__global__ __launch_bounds__(256)
void transpose_cast(const float* __restrict__ W, unsigned short* __restrict__ Wt,
                    int K, int N)
{
    __shared__ float tile[32][33];
    const int n0 = blockIdx.x * 32;
    const int k0 = blockIdx.y * 32;
    const int tx = threadIdx.x & 31;
    const int ty = threadIdx.x >> 5;
    #pragma unroll
    for (int i = 0; i < 32; i += 8)
        tile[ty + i][tx] = W[(size_t)(k0 + ty + i) * N + n0 + tx];
    __syncthreads();
    #pragma unroll
    for (int i = 0; i < 32; i += 8)
        Wt[(size_t)(n0 + ty + i) * K + k0 + tx] = f2bf_bits(tile[tx][ty + i]);
}

// ---------------------------------------------------------------------------
// 256x256 bf16 MFMA GEMM — R13: balanced-phase schedule.
// Pipe arithmetic: per K-tile/CU, LDS reads (192 b128 = 2304 cyc) ~= MFMA
// (2483 cyc); they only overlap if each phase carries reads under its MFMA
// shadow (620 cyc/phase). R5's placement was 4/8/0/12 (p3's 1152-cyc burst
// exposed); R13 rebalances to 8/4/6/6 by moving the buf^1 residency gate
// (vmcnt(0)+bar) from p3 to end-of-p1. Two barriers per tile total.
//   p0: issue b23+a45 -> lgkm(8) -> Q(0,0)
//   p1: issue a67 -> lgkm(8) -> Q(0,2) -> vmcnt(0) -> BAR1 -> STAGE B(T+2)
//   p2: issue next a0-2 -> lgkm(6|0) -> Q(4,0) -> BAR2 -> STAGE A(T+2)
//   p3: issue next a3,b01 -> Q(4,2)   (operands all retired by p2's wait)
// Hazards: buf.B frag reads consumed by Q00/Q02 before BAR1 (stage B);
// buf.A consumed by Q00/Q40 before BAR2 (stage A); buf^1 reads (p2/p3/next
// p0,p1) precede its restaging at T+1's BAR1/BAR2. vmcnt(0) at p1 drains
// T+1's stages (issued 1 tile ago -> free in steady state).
// ---------------------------------------------------------------------------
template<int OUT_BF16>
__global__ __launch_bounds__(512, 2)
void gemm256_8ph(const unsigned short* __restrict__ A,
                 const unsigned short* __restrict__ Bt,
                 const float* __restrict__ bias,
                 void* __restrict__ Cout,
                 int M, int N, int K, int nbx)
{
    __shared__ __align__(16) short smem_s[65536];   // 128 KiB

    const int t    = threadIdx.x;
    const int w    = t >> 6;
    const int lane = t & 63;
    const int wm   = w >> 2;
    const int wn   = w & 3;
    const int lr   = lane & 15;
    const int hi   = lane >> 4;
    const int lo7  = lane & 7;

    const int nwg  = gridDim.x;
    const int orig = blockIdx.x;
    const int wgid = (orig & 7) * (nwg >> 3) + (orig >> 3);
    const int by = wgid / nbx, bx = wgid % nbx;
    const int bm0 = by * 256, bn0 = bx * 256;

    const int nt = K >> 6;

    const int srow = t >> 3;
    const int scol = ((t & 7) ^ (srow & 7)) * 8;
    const unsigned short* Ag = A  + (size_t)(bm0 + srow) * K + scol;
    const unsigned short* Bg = Bt + (size_t)(bn0 + srow) * K + scol;
    const int wbase = w * 1024;

    auto STAGE = [&](int which, int half, int tile) {
        const unsigned short* g0 = (which ? Bg : Ag)
                                 + (size_t)(half * 128) * K + (size_t)tile * 64;
        char* d0 = (char*)smem_s + ((tile & 1) * 65536 + which * 32768
                                    + half * 16384 + wbase);
        gl_lds16(g0,                d0);
        gl_lds16(g0 + (size_t)64*K, d0 + 8192);
    };

    short8v a[8][2], b[4][2];
    f32x4 acc[8][4] = {};

    auto LDA = [&](int buf, int m, int ks) {
        a[m][ks] = *(const short8v*)&smem_s[buf*32768 + wm*8192
                        + (m*16 + lr)*64 + (((ks*4 + hi) ^ lo7) * 8)];
    };
    auto LDB = [&](int buf, int n, int ks) {
        b[n][ks] = *(const short8v*)&smem_s[buf*32768 + 16384 + (wn>>1)*8192
                        + ((wn&1)*64 + n*16 + lr)*64 + (((ks*4 + hi) ^ lo7) * 8)];
    };
    auto QUAD = [&](int mlo, int nlo) {      // ks-outer (R12, neutral-safe)
        __builtin_amdgcn_s_setprio(1);
        #pragma unroll
        for (int ks = 0; ks < 2; ++ks)
            #pragma unroll
            for (int mi = 0; mi < 4; ++mi)
                #pragma unroll
                for (int ni = 0; ni < 2; ++ni)
                    acc[mlo+mi][nlo+ni] = __builtin_amdgcn_mfma_f32_16x16x32_bf16(
                        a[mlo+mi][ks], b[nlo+ni][ks], acc[mlo+mi][nlo+ni], 0, 0, 0);
        __builtin_amdgcn_s_setprio(0);
    };

    // ---- prologue: stage tiles 0,1; tile 0 resident; preload 12 frags ----
    STAGE(0,0,0); STAGE(0,1,0); STAGE(1,0,0); STAGE(1,1,0);
    STAGE(0,0,1); STAGE(0,1,1); STAGE(1,0,1); STAGE(1,1,1);
    asm volatile("s_waitcnt vmcnt(8)" ::: "memory");
    __builtin_amdgcn_s_barrier();
    #pragma unroll
    for (int m = 0; m < 4; ++m) { LDA(0,m,0); LDA(0,m,1); }
    LDB(0,0,0); LDB(0,0,1); LDB(0,1,0); LDB(0,1,1);   // 12 outstanding

    for (int T = 0; T < nt; ++T) {
        const int buf  = T & 1;
        const int nbuf = buf ^ 1;
        const bool has1 = (T + 1 < nt);
        const bool has2 = (T + 2 < nt);

        // ---- p0: issue b23+a45 (8); retire prior 12 (keep 8); Q(0,0) ----
        LDB(buf,2,0); LDB(buf,2,1); LDB(buf,3,0); LDB(buf,3,1);
        LDA(buf,4,0); LDA(buf,4,1); LDA(buf,5,0); LDA(buf,5,1);
        asm volatile("s_waitcnt lgkmcnt(8)" ::: "memory");
        __builtin_amdgcn_sched_barrier(0);
        QUAD(0,0);
        // ---- p1: issue a67 (4); retire b23 (keep a45+a67=8); Q(0,2);
        //      vmcnt(0): T+1 stages drained; BAR1; stage B(T+2) ----
        LDA(buf,6,0); LDA(buf,6,1); LDA(buf,7,0); LDA(buf,7,1);
        asm volatile("s_waitcnt lgkmcnt(8)" ::: "memory");
        __builtin_amdgcn_sched_barrier(0);
        QUAD(0,2);
        asm volatile("s_waitcnt vmcnt(0)" ::: "memory");
        __builtin_amdgcn_s_barrier();        // BAR1: T+1 resident for all;
        if (has2) { STAGE(1,0,T+2); STAGE(1,1,T+2); }   // buf.B reads done
        // ---- p2: issue next-tile a0-2 (6); retire a4-7; Q(4,0); BAR2 ----
        if (has1) {
            LDA(nbuf,0,0); LDA(nbuf,0,1); LDA(nbuf,1,0); LDA(nbuf,1,1);
            LDA(nbuf,2,0); LDA(nbuf,2,1);
            asm volatile("s_waitcnt lgkmcnt(6)" ::: "memory");
        } else {
            asm volatile("s_waitcnt lgkmcnt(0)" ::: "memory");
        }
        __builtin_amdgcn_sched_barrier(0);
        QUAD(4,0);
        __builtin_amdgcn_s_barrier();        // BAR2: buf.A reads done
        if (has2) { STAGE(0,0,T+2); STAGE(0,1,T+2); }
        // ---- p3: issue next-tile a3,b01 (6); Q(4,2) ----
        if (has1) {
            LDA(nbuf,3,0); LDA(nbuf,3,1);
            LDB(nbuf,0,0); LDB(nbuf,0,1); LDB(nbuf,1,0); LDB(nbuf,1,1);
        }
        __builtin_amdgcn_sched_barrier(0);   // pin: reads issue before Q(4,2)
        QUAD(4,2);
    }

    // ---- epilogue: C/D layout col=lane&15, row=hi*4+j ----
    const int r0 = bm0 + wm*128 + hi*4;
    const int cb = bn0 + wn*64 + lr;
    float bv[4];
    #pragma unroll
    for (int n = 0; n < 4; ++n) bv[n] = bias[cb + n*16];
    if (OUT_BF16) {
        unsigned short* Cb = (unsigned short*)Cout;
        #pragma unroll
        for (int m = 0; m < 8; ++m)
            #pragma unroll
            for (int j = 0; j < 4; ++j) {
                unsigned short* rp = Cb + (size_t)(r0 + m*16 + j) * N;
                #pragma unroll
                for (int n = 0; n < 4; ++n)
                    rp[cb + n*16] = f2bf_bits(acc[m][n][j] + bv[n]);
            }
    } else {
        float* Cf = (float*)Cout;
        #pragma unroll
        for (int m = 0; m < 8; ++m)
            #pragma unroll
            for (int j = 0; j < 4; ++j) {
                float* rp = Cf + (size_t)(r0 + m*16 + j) * N;
                #pragma unroll
                for (int n = 0; n < 4; ++n)
                    rp[cb + n*16] = acc[m][n][j] + bv[n];
            }
    }
}

// ---------------------------------------------------------------------------
// R9 attention (unchanged): one wave per position, all-register, no LDS.
// ---------------------------------------------------------------------------
__global__ __launch_bounds__(256)
void attn_mfma_kernel(const unsigned short* __restrict__ qkv,
                      unsigned short* __restrict__ aout)
{
    const int l  = threadIdx.x & 63;
    const int wv = threadIdx.x >> 6;
    const int p  = blockIdx.x * 4 + wv;
    const int lr = l & 15;
    const int hi = l >> 4;
    const unsigned short* base = qkv + (size_t)p * N_QKV;

    short8v qf0 = *(const short8v*)(base +        lr*64 +      hi*8);
    short8v qf1 = *(const short8v*)(base +        lr*64 + 32 + hi*8);
    short8v kf0 = *(const short8v*)(base + 1024 + lr*64 +      hi*8);
    short8v kf1 = *(const short8v*)(base + 1024 + lr*64 + 32 + hi*8);

    f32x4 s = {};
    s = __builtin_amdgcn_mfma_f32_16x16x32_bf16(kf0, qf0, s, 0, 0, 0);
    s = __builtin_amdgcn_mfma_f32_16x16x32_bf16(kf1, qf1, s, 0, 0, 0);

    float qsq = 0.f, ksq = 0.f;
    #pragma unroll
    for (int i = 0; i < 8; ++i) {
        float q0 = bf2f((unsigned short)qf0[i]), q1 = bf2f((unsigned short)qf1[i]);
        float k0 = bf2f((unsigned short)kf0[i]), k1 = bf2f((unsigned short)kf1[i]);
        qsq = fmaf(q0, q0, fmaf(q1, q1, qsq));
        ksq = fmaf(k0, k0, fmaf(k1, k1, ksq));
    }
    qsq += __shfl_xor(qsq, 16); qsq += __shfl_xor(qsq, 32);
    ksq += __shfl_xor(ksq, 16); ksq += __shfl_xor(ksq, 32);

    const float mq = sqrtf(qsq);

    float P[4];
    #pragma unroll
    for (int j = 0; j < 4; ++j) {
        float ksg = __shfl(ksq, hi * 4 + j);
        float dsq = fmaxf(qsq + ksg - 2.f * s[j], 0.f);
        dsq = dsq * (1.f + CURV * cosf(sqrtf(dsq + EPS_F)));
        P[j] = mq * sqrtf(ksg) / (dsq + EPS_F);
    }
    float mx = fmaxf(fmaxf(P[0], P[1]), fmaxf(P[2], P[3]));
    mx = fmaxf(mx, __shfl_xor(mx, 16));
    mx = fmaxf(mx, __shfl_xor(mx, 32));
    float sm = 0.f;
    #pragma unroll
    for (int j = 0; j < 4; ++j) { P[j] = expf(P[j] - mx); sm += P[j]; }
    sm += __shfl_xor(sm, 16); sm += __shfl_xor(sm, 32);
    const float inv = 1.f / sm;

    unsigned int w0 = (unsigned)f2bf_bits(P[0] * inv)
                    | ((unsigned)f2bf_bits(P[1] * inv) << 16);
    unsigned int w1 = (unsigned)f2bf_bits(P[2] * inv)
                    | ((unsigned)f2bf_bits(P[3] * inv) << 16);
    const int s0 = lr + (((2 * hi)     & 3) << 4);
    const int s1 = lr + (((2 * hi + 1) & 3) << 4);
    unsigned int a0 = __shfl((int)w0, s0), a1 = __shfl((int)w1, s0);
    unsigned int a2 = __shfl((int)w0, s1), a3 = __shfl((int)w1, s1);
    if (hi >= 2) { a0 = a1 = a2 = a3 = 0; }
    unsigned int pa_u[4] = {a0, a1, a2, a3};
    short8v pa = *(short8v*)pa_u;

    const unsigned short* vb = base + 2048;
    unsigned short* orow = aout + (size_t)p * D_MODEL;
    #pragma unroll
    for (int c = 0; c < 4; ++c) {
        unsigned int bu[4];
        #pragma unroll
        for (int e2 = 0; e2 < 4; ++e2) {
            int g0 = (hi * 8 + e2 * 2) & 15;
            int g1 = (hi * 8 + e2 * 2 + 1) & 15;
            unsigned int lo = vb[g0 * 64 + c * 16 + lr];
            unsigned int hi16 = vb[g1 * 64 + c * 16 + lr];
            bu[e2] = lo | (hi16 << 16);
        }
        short8v bv = *(short8v*)bu;
        f32x4 o = {};
        o = __builtin_amdgcn_mfma_f32_16x16x32_bf16(pa, bv, o, 0, 0, 0);
        #pragma unroll
        for (int j = 0; j < 4; ++j)
            orow[(hi * 4 + j) * 64 + c * 16 + lr] = f2bf_bits(o[j]);
    }
}

// ---------------------------------------------------------------------------
extern "C" void kernel_launch(void* const* d_in, const int* in_sizes, int n_in,
                              void* d_out, int out_size, void* d_ws, size_t ws_size,
                              hipStream_t stream)
{
    const float* x     = (const float*)d_in[0];   // 16384 x 1024
    const float* W_qkv = (const float*)d_in[1];   // 1024 x 3072
    const float* b_qkv = (const float*)d_in[2];   // 3072
    const float* W_out = (const float*)d_in[3];   // 1024 x 1024
    const float* b_out = (const float*)d_in[4];   // 1024
    float* out = (float*)d_out;                   // 16384 x 1024

    // workspace: [0,96M) qkv bf16 | [96M,128M) xb/ab bf16 | Wt1 6M | Wt2 2M
    char* ws = (char*)d_ws;
    unsigned short* qkvb = (unsigned short*)ws;
    unsigned short* xb   = (unsigned short*)(ws + (size_t)M_TOTAL * N_QKV * 2);
    unsigned short* ab   = xb;   // alias: xb dead after GEMM1
    unsigned short* Wt1  = (unsigned short*)(ws + (size_t)M_TOTAL * N_QKV * 2
                                                + (size_t)M_TOTAL * D_MODEL * 2);
    unsigned short* Wt2  = Wt1 + (size_t)N_QKV * D_MODEL;

    // 0a) cast x -> bf16
    {
        int ngroups = M_TOTAL * D_MODEL / 4;
        cast_f32_bf16<<<ngroups / 256, 256, 0, stream>>>(x, xb, ngroups);
    }
    // 0b) transpose+cast weights
    {
        dim3 g(N_QKV / 32, D_MODEL / 32);
        transpose_cast<<<g, 256, 0, stream>>>(W_qkv, Wt1, D_MODEL, N_QKV);
        dim3 g2(D_MODEL / 32, D_MODEL / 32);
        transpose_cast<<<g2, 256, 0, stream>>>(W_out, Wt2, D_MODEL, D_MODEL);
    }

    // 1) qkv = x @ W_qkv + b_qkv  (bf16 out)
    {
        int nbx = N_QKV / 256;                 // 12
        int nwg = (M_TOTAL / 256) * nbx;       // 768 (%8==0)
        gemm256_8ph<1><<<nwg, 512, 0, stream>>>(xb, Wt1, b_qkv, qkvb,
                                                M_TOTAL, N_QKV, D_MODEL, nbx);
    }

    // 2) per-position head attention — 1 wave/position, 4 positions/block
    attn_mfma_kernel<<<M_TOTAL / 4, 256, 0, stream>>>(qkvb, ab);

    // 3) out = ab @ W_out + b_out  (fp32 out)
    {
        int nbx = D_MODEL / 256;               // 4
        int nwg = (M_TOTAL / 256) * nbx;       // 256 (%8==0)
        gemm256_8ph<0><<<nwg, 512, 0, stream>>>(ab, Wt2, b_out, out,
                                                M_TOTAL, D_MODEL, D_MODEL, nbx);
    }
}